// Round 13
// baseline (157.112 us; speedup 1.0000x reference)
//
#include <hip/hip_runtime.h>
#include <math.h>

#define BB 4
#define NN 1024
#define CC 384
#define KK 10
#define NKK (NN*KK)

typedef __attribute__((ext_vector_type(8))) short short8v;
typedef __attribute__((ext_vector_type(8))) unsigned short ushort8v;
typedef __attribute__((ext_vector_type(4))) float f32x4;

template <int NA>
__device__ __forceinline__ void wave_sum_arr(float* a) {
  #pragma unroll
  for (int off = 32; off > 0; off >>= 1) {
    float t[NA];
    #pragma unroll
    for (int u = 0; u < NA; ++u) t[u] = __shfl_xor(a[u], off, 64);
    #pragma unroll
    for (int u = 0; u < NA; ++u) a[u] += t[u];
  }
}

__device__ __forceinline__ unsigned short f2bf(float x) {
  unsigned int b = __float_as_uint(x);
  return (unsigned short)((b + 0x7fffu + ((b >> 16) & 1u)) >> 16);  // RNE
}
__device__ __forceinline__ float bf2f(unsigned short h) {
  return __uint_as_float(((unsigned int)h) << 16);
}

// ======== fused prep + M1 split-K GEMM, partitioned by blockIdx ========
#define NB_CVT  (BB * NN * CC / 1024)        // 1536
#define NB_PB   (2 * CC * CC / 256)          // 1152
#define NB_PREP (NB_CVT + NB_PB + 3)
__global__ __launch_bounds__(256) void prep_gemm_kernel(
    const float* __restrict__ q,
    const float* __restrict__ W1, const float* __restrict__ b1,
    const float* __restrict__ bv, const float* __restrict__ bk,
    const float* __restrict__ Wk, const float* __restrict__ Wv,
    unsigned short* __restrict__ qh, unsigned short* __restrict__ ql,
    unsigned short* __restrict__ Wt,
    float* __restrict__ bias_uv, float* __restrict__ bias_pb,
    float* __restrict__ M1p) {
  int blk = blockIdx.x;
  int tid = threadIdx.x;
  if (blk < NB_CVT) {
    int i = (blk * 256 + tid) * 4;
    float4 v = *reinterpret_cast<const float4*>(q + i);
    float x[4] = {v.x, v.y, v.z, v.w};
    #pragma unroll
    for (int j = 0; j < 4; ++j) {
      unsigned short h = f2bf(x[j]);
      qh[i + j] = h;
      ql[i + j] = f2bf(x[j] - bf2f(h));
    }
    return;
  }
  if (blk < NB_CVT + NB_PB) {
    int idx = (blk - NB_CVT) * 256 + tid;    // 768*384
    int n = idx / CC, k = idx % CC;
    float v;
    if (n < CC) v = Wk[(size_t)k * CC + n];
    else        v = Wk[(size_t)CC * CC + k * CC + (n - CC)] - Wk[(size_t)k * CC + (n - CC)];
    Wt[(size_t)n * CC + k] = f2bf(v);
    return;
  }
  if (blk < NB_PREP) {
    int j = (blk - NB_CVT - NB_PB) * 256 + tid;
    if (j >= 2 * CC) return;
    if (j < CC) { bias_uv[j] = 0.f; bias_pb[j] = 0.f; }
    else {
      int c = j - CC;
      float s = b1[c];
      for (int i = 0; i < CC; ++i) s += bv[i] * W1[i * CC + c];
      bias_uv[j] = s;          // c1
      bias_pb[j] = bk[c];
    }
    return;
  }
  // ---- gemm128: M1p[z] = Wv @ W1_top (K-slice z), 72 blocks (3x3x8) ----
  {
    int r = blk - NB_PREP;
    int bx = r % 3, by = (r / 3) % 3, bz = r / 9;
    __shared__ float As[16][132];
    __shared__ float Bs[16][128];
    int tx = tid & 15, ty = tid >> 4;
    int row0 = by * 128, col0 = bx * 128;
    int k0 = bz * 48;
    float acc[8][8] = {};
    int arow = tid >> 2, akc = (tid & 3) << 2;
    int brow = tid >> 5, bcol = (tid & 31) << 2;
    for (int kt = k0; kt < k0 + 48; kt += 16) {
      #pragma unroll
      for (int h = 0; h < 2; ++h) {
        int rr = arow + 64 * h;
        float4 av = *reinterpret_cast<const float4*>(Wv + (size_t)(row0 + rr) * CC + kt + akc);
        As[akc + 0][rr] = av.x; As[akc + 1][rr] = av.y;
        As[akc + 2][rr] = av.z; As[akc + 3][rr] = av.w;
      }
      #pragma unroll
      for (int h = 0; h < 2; ++h) {
        int rr = brow + 8 * h;
        float4 bv4 = *reinterpret_cast<const float4*>(W1 + (size_t)(kt + rr) * CC + col0 + bcol);
        *reinterpret_cast<float4*>(&Bs[rr][bcol]) = bv4;
      }
      __syncthreads();
      #pragma unroll
      for (int kk = 0; kk < 16; ++kk) {
        float4 a0 = *reinterpret_cast<const float4*>(&As[kk][ty << 2]);
        float4 a1 = *reinterpret_cast<const float4*>(&As[kk][64 + (ty << 2)]);
        float4 b0 = *reinterpret_cast<const float4*>(&Bs[kk][tx << 2]);
        float4 b1 = *reinterpret_cast<const float4*>(&Bs[kk][64 + (tx << 2)]);
        float av_[8] = {a0.x, a0.y, a0.z, a0.w, a1.x, a1.y, a1.z, a1.w};
        float bv_[8] = {b0.x, b0.y, b0.z, b0.w, b1.x, b1.y, b1.z, b1.w};
        #pragma unroll
        for (int i = 0; i < 8; ++i)
          #pragma unroll
          for (int j = 0; j < 8; ++j) acc[i][j] += av_[i] * bv_[j];
      }
      __syncthreads();
    }
    float* Cz = M1p + (size_t)bz * CC * CC;
    #pragma unroll
    for (int i = 0; i < 8; ++i) {
      int row = row0 + (ty << 2) + (i & 3) + ((i & 4) << 4);
      if (row >= CC) continue;
      #pragma unroll
      for (int h = 0; h < 2; ++h) {
        int col = col0 + 64 * h + (tx << 2);
        if (col >= CC) continue;
        float4 rv;
        rv.x = acc[i][4 * h + 0]; rv.y = acc[i][4 * h + 1];
        rv.z = acc[i][4 * h + 2]; rv.w = acc[i][4 * h + 3];
        *reinterpret_cast<float4*>(Cz + (size_t)row * CC + col) = rv;
      }
    }
  }
}

// ------- Buv_t[n][k] = (n<384 ? M1[k][n] : W1_bot[k][n-384]) split hi/lo -------------
__global__ void pack_uv_split_kernel(const float* __restrict__ M1p, const float* __restrict__ W1,
                                     unsigned short* __restrict__ Buvh,
                                     unsigned short* __restrict__ Buvl) {
  int idx = blockIdx.x * 256 + threadIdx.x;   // 384*768
  int k = idx / (2 * CC), n = idx % (2 * CC);
  float val;
  if (n < CC) {
    float s = 0.f;
    #pragma unroll
    for (int p = 0; p < 8; ++p) s += M1p[(size_t)p * CC * CC + (size_t)k * CC + n];
    val = s;
  } else {
    val = W1[(size_t)(CC + k) * CC + (n - CC)];
  }
  unsigned short h = f2bf(val);
  Buvh[(size_t)n * CC + k] = h;
  Buvl[(size_t)n * CC + k] = f2bf(val - bf2f(h));
}

// ======== fused: [0,384) MFMA GEMM (verified) + [384,1408) knn (verified r10) ========
#define GEMM_NB 384   // 2 paths x 32 by x 6 bx
__global__ __launch_bounds__(256) void gemm_knn_kernel(
    const unsigned short* __restrict__ qh, const unsigned short* __restrict__ ql,
    const unsigned short* __restrict__ Buvh, const unsigned short* __restrict__ Buvl,
    const unsigned short* __restrict__ Wt,
    float* __restrict__ Cuv, float* __restrict__ Cpb,
    const float* __restrict__ bias_uv, const float* __restrict__ bias_pb,
    const float* __restrict__ q_pos, int* __restrict__ idxk, float* __restrict__ meta) {
  __shared__ __align__(16) char smem[32768];
  int blk = blockIdx.x;
  int tid = threadIdx.x;
  int lane = tid & 63, wave = tid >> 6;

  if (blk < GEMM_NB) {
    // ================= MFMA GEMM path (verbatim) =================
    int path = blk / 192;
    int rem = blk % 192;
    int by = rem / 6, bx = rem % 6;
    unsigned short* Ah  = (unsigned short*)smem;
    unsigned short* Alo = (unsigned short*)(smem + 8192);
    unsigned short* Bhs = (unsigned short*)(smem + 16384);
    unsigned short* Bls = (unsigned short*)(smem + 24576);
    const unsigned short* Bh = path ? Wt : Buvh;
    float* Cm = path ? Cpb : Cuv;
    const float* bias = path ? bias_pb : bias_uv;
    int m0 = by * 128, n0 = bx * 128;
    f32x4 acc[4][4];
    #pragma unroll
    for (int i = 0; i < 4; ++i)
      #pragma unroll
      for (int j = 0; j < 4; ++j) acc[i][j] = (f32x4){0.f, 0.f, 0.f, 0.f};
    int rl = lane & 15, kg = lane >> 4;
    for (int k0 = 0; k0 < CC; k0 += 32) {
      #pragma unroll
      for (int j = 0; j < 2; ++j) {
        int id = tid + 256 * j;
        int r = id >> 2, s = id & 3;
        int sw = (s ^ (r & 3)) * 8;
        *reinterpret_cast<ushort8v*>(Ah + r * 32 + sw) =
            *reinterpret_cast<const ushort8v*>(qh + (size_t)(m0 + r) * CC + k0 + s * 8);
        *reinterpret_cast<ushort8v*>(Bhs + r * 32 + sw) =
            *reinterpret_cast<const ushort8v*>(Bh + (size_t)(n0 + r) * CC + k0 + s * 8);
        if (!path) {
          *reinterpret_cast<ushort8v*>(Alo + r * 32 + sw) =
              *reinterpret_cast<const ushort8v*>(ql + (size_t)(m0 + r) * CC + k0 + s * 8);
          *reinterpret_cast<ushort8v*>(Bls + r * 32 + sw) =
              *reinterpret_cast<const ushort8v*>(Buvl + (size_t)(n0 + r) * CC + k0 + s * 8);
        }
      }
      __syncthreads();
      short8v afh[4], bfh[4], afl[4], bfl[4];
      #pragma unroll
      for (int f = 0; f < 4; ++f) {
        int ar = (wave & 1) * 64 + f * 16 + rl;
        int aof = ar * 32 + (kg ^ (ar & 3)) * 8;
        int br = (wave >> 1) * 64 + f * 16 + rl;
        int bof = br * 32 + (kg ^ (br & 3)) * 8;
        afh[f] = *reinterpret_cast<const short8v*>(Ah + aof);
        bfh[f] = *reinterpret_cast<const short8v*>(Bhs + bof);
        if (!path) {
          afl[f] = *reinterpret_cast<const short8v*>(Alo + aof);
          bfl[f] = *reinterpret_cast<const short8v*>(Bls + bof);
        }
      }
      #pragma unroll
      for (int i = 0; i < 4; ++i) {
        #pragma unroll
        for (int j = 0; j < 4; ++j) {
          acc[i][j] = __builtin_amdgcn_mfma_f32_16x16x32_bf16(afh[i], bfh[j], acc[i][j], 0, 0, 0);
          if (!path) {
            acc[i][j] = __builtin_amdgcn_mfma_f32_16x16x32_bf16(afh[i], bfl[j], acc[i][j], 0, 0, 0);
            acc[i][j] = __builtin_amdgcn_mfma_f32_16x16x32_bf16(afl[i], bfh[j], acc[i][j], 0, 0, 0);
          }
        }
      }
      __syncthreads();
    }
    #pragma unroll
    for (int i = 0; i < 4; ++i) {
      #pragma unroll
      for (int j = 0; j < 4; ++j) {
        int col = n0 + (wave >> 1) * 64 + j * 16 + rl;
        float bcol_v = bias[col];
        #pragma unroll
        for (int r = 0; r < 4; ++r) {
          int row = m0 + (wave & 1) * 64 + i * 16 + kg * 4 + r;
          Cm[(size_t)row * (2 * CC) + col] = acc[i][j][r] + bcol_v;
        }
      }
    }
    return;
  }

  // ================= knn path (verbatim; sp4 in smem union) =================
  {
    int kblk = blk - GEMM_NB;            // [0, 1024)
    int b = kblk >> 8;
    int ng = kblk & 255;
    int n = ng * 4 + wave;
    int bn = b * NN + n;
    float4* sp4 = (float4*)smem;

    const float* qp = q_pos + (size_t)b * NN * 3;
    for (int i = tid; i < NN; i += 256) {
      float x = qp[i * 3 + 0], y = qp[i * 3 + 1], z = qp[i * 3 + 2];
      sp4[i] = (float4){x, y, z, x * x + y * y + z * z};
    }
    __syncthreads();

    int nb[KK];
    {
      float4 me = sp4[n];
      float px = me.x, py = me.y, pz = me.z, sp = me.w;
      float bd[KK]; int bi[KK];
      #pragma unroll
      for (int s = 0; s < KK; ++s) { bd[s] = 1e30f; bi[s] = -1; }
      #pragma unroll 4
      for (int j = 0; j < 16; ++j) {
        int m = lane + (j << 6);
        float4 c = sp4[m];
        float dot = fmaf(px, c.x, fmaf(py, c.y, pz * c.z));
        float d = fmaf(-2.f, dot, sp + c.w);
        d = fmaxf(d, 0.f);
        if (d < bd[KK - 1]) {
          bd[KK - 1] = d; bi[KK - 1] = m;
          #pragma unroll
          for (int s = KK - 1; s >= 1; --s) {
            if (bd[s] < bd[s - 1]) {
              float td = bd[s]; bd[s] = bd[s - 1]; bd[s - 1] = td;
              int ti = bi[s]; bi[s] = bi[s - 1]; bi[s - 1] = ti;
            }
          }
        }
      }
      #pragma unroll
      for (int s = 0; s < KK; ++s) {
        float d = bd[0]; int i = bi[0];
        #pragma unroll
        for (int off = 32; off > 0; off >>= 1) {
          float od = __shfl_xor(d, off, 64);
          int oi = __shfl_xor(i, off, 64);
          if (od < d || (od == d && oi < i)) { d = od; i = oi; }
        }
        if (bi[0] == i) {
          #pragma unroll
          for (int u = 0; u < KK - 1; ++u) { bd[u] = bd[u + 1]; bi[u] = bi[u + 1]; }
          bd[KK - 1] = 1e30f; bi[KK - 1] = -1;
        }
        nb[s] = i;   // uniform across lanes
      }
    }

    float sclx, scly, sclz;
    {
      float mxx = -1e30f, mnx = 1e30f, mxy = -1e30f, mny = 1e30f, mxz = -1e30f, mnz = 1e30f;
      #pragma unroll
      for (int k2 = 0; k2 < KK; ++k2) {
        float4 c = sp4[nb[k2]];
        mxx = fmaxf(mxx, c.x); mnx = fminf(mnx, c.x);
        mxy = fmaxf(mxy, c.y); mny = fminf(mny, c.y);
        mxz = fmaxf(mxz, c.z); mnz = fminf(mnz, c.z);
      }
      sclx = (mxx - mnx) * 0.5f; scly = (mxy - mny) * 0.5f; sclz = (mxz - mnz) * 0.5f;
    }

    int myn = 0;
    #pragma unroll
    for (int k = 0; k < KK; ++k) if (lane == k) myn = nb[k];
    float* mrow = meta + (size_t)bn * 36;
    if (lane < KK) {
      idxk[(size_t)bn * KK + lane] = myn;
      float4 c = sp4[myn];
      mrow[lane * 3 + 0] = c.x;
      mrow[lane * 3 + 1] = c.y;
      mrow[lane * 3 + 2] = c.z;
    }
    if (lane == 0) { mrow[30] = sclx; mrow[31] = scly; mrow[32] = sclz; }
  }
}

// ---- templated three_nn scan for C points (verified scan/extraction, static arrays) --
template <int C>
__device__ __forceinline__ void three_nn_scan(
    const float4* sp4, const float* s_shp, int pbase, int lane,
    float (&owd)[3][3], int (&owi)[3][3]) {
  float px[C], py[C], pz[C], ps[C];
  #pragma unroll
  for (int j = 0; j < C; ++j) {
    int p = pbase + j;
    px[j] = s_shp[p * 3 + 0]; py[j] = s_shp[p * 3 + 1]; pz[j] = s_shp[p * 3 + 2];
    ps[j] = fmaf(px[j], px[j], fmaf(py[j], py[j], pz[j] * pz[j]));
  }
  float d0[C], d1[C], d2[C]; int i0[C], i1[C], i2[C];
  #pragma unroll
  for (int j = 0; j < C; ++j) { d0[j] = d1[j] = d2[j] = 1e30f; i0[j] = i1[j] = i2[j] = -1; }
  #pragma unroll 4
  for (int it = 0; it < 16; ++it) {
    int m = lane + (it << 6);
    float4 c = sp4[m];
    #pragma unroll
    for (int j = 0; j < C; ++j) {
      float dot = fmaf(px[j], c.x, fmaf(py[j], c.y, pz[j] * c.z));
      float d = fmaf(-2.f, dot, ps[j] + c.w);
      d = fmaxf(d, 0.f);
      bool c2 = d < d2[j], c1 = d < d1[j], c0 = d < d0[j];
      d2[j] = c1 ? d1[j] : (c2 ? d : d2[j]);  i2[j] = c1 ? i1[j] : (c2 ? m : i2[j]);
      d1[j] = c0 ? d0[j] : (c1 ? d : d1[j]);  i1[j] = c0 ? i0[j] : (c1 ? m : i1[j]);
      d0[j] = c0 ? d : d0[j];                 i0[j] = c0 ? m : i0[j];
    }
  }
  #pragma unroll
  for (int s = 0; s < 3; ++s) {
    float d[C]; int ii[C];
    #pragma unroll
    for (int j = 0; j < C; ++j) { d[j] = d0[j]; ii[j] = i0[j]; }
    #pragma unroll
    for (int off = 32; off > 0; off >>= 1) {
      #pragma unroll
      for (int j = 0; j < C; ++j) {
        float od = __shfl_xor(d[j], off, 64);
        int oi = __shfl_xor(ii[j], off, 64);
        if (od < d[j] || (od == d[j] && oi < ii[j])) { d[j] = od; ii[j] = oi; }
      }
    }
    #pragma unroll
    for (int j = 0; j < C; ++j) {
      if (i0[j] == ii[j]) {
        d0[j] = d1[j]; i0[j] = i1[j]; d1[j] = d2[j]; i1[j] = i2[j]; d2[j] = 1e30f; i2[j] = -1;
      }
      owd[s][j] = d[j]; owi[s][j] = ii[j];
    }
  }
}

// ======== interp v3: mlp (waves 0-1) || sp4 staging (waves 2-3) -> scan -> final ======
__global__ __launch_bounds__(256) void interp_kernel(
    const float* __restrict__ Cat_uv, const float* __restrict__ Cat_pb,
    const float* __restrict__ lng, const float* __restrict__ lnb,
    const float* __restrict__ W2, const float* __restrict__ q_pos,
    const int* __restrict__ idxk, const float* __restrict__ meta,
    float* __restrict__ out) {
  int bn = blockIdx.x;
  int b = bn >> 10;
  int tid = threadIdx.x;
  int wave = tid >> 6, lane = tid & 63;
  __shared__ float4 sp4[NN];
  __shared__ float s_shp[KK * 3];
  __shared__ float s_w[KK][3];
  __shared__ int s_i[KK][3];

  if (wave >= 2) {
    // ---- waves 2-3: stage positions (x,y,z,|p|^2) ----
    const float* qp = q_pos + (size_t)b * NN * 3;
    for (int i = tid - 128; i < NN; i += 128) {
      float x = qp[i * 3 + 0], y = qp[i * 3 + 1], z = qp[i * 3 + 2];
      sp4[i] = (float4){x, y, z, x * x + y * y + z * z};
    }
  } else {
    // ---- waves 0-1: mlp for this bn (verbatim r10 body; shp -> LDS) ----
    int kb = wave * 5;
    int nb5[5];
    #pragma unroll
    for (int kk = 0; kk < 5; ++kk) nb5[kk] = idxk[(size_t)bn * KK + kb + kk];
    float Vv[6], lg[6], lb[6], w2a[6], w2b[6], w2c[6];
    const float* Vrow = Cat_uv + (size_t)bn * (2 * CC) + CC;
    #pragma unroll
    for (int i = 0; i < 6; ++i) {
      int c = lane + (i << 6);
      Vv[i] = Vrow[c];
      lg[i] = lng[c]; lb[i] = lnb[c];
      w2a[i] = W2[c * 3 + 0]; w2b[i] = W2[c * 3 + 1]; w2c[i] = W2[c * 3 + 2];
    }
    float hk[5][6];
    float sum[5];
    #pragma unroll
    for (int kk = 0; kk < 5; ++kk) {
      const float* Urow = Cat_uv + ((size_t)b * NN + nb5[kk]) * (2 * CC);
      float s = 0.f;
      #pragma unroll
      for (int i = 0; i < 6; ++i) {
        hk[kk][i] = Urow[lane + (i << 6)] + Vv[i];
        s += hk[kk][i];
      }
      sum[kk] = s;
    }
    wave_sum_arr<5>(sum);
    float mu[5], var[5];
    #pragma unroll
    for (int kk = 0; kk < 5; ++kk) {
      mu[kk] = sum[kk] * (1.0f / CC);
      float v = 0.f;
      #pragma unroll
      for (int i = 0; i < 6; ++i) { float d = hk[kk][i] - mu[kk]; v += d * d; }
      var[kk] = v;
    }
    wave_sum_arr<5>(var);
    float o[15];
    #pragma unroll
    for (int kk = 0; kk < 5; ++kk) {
      float rstd = 1.0f / sqrtf(var[kk] * (1.0f / CC) + 1e-5f);
      float o0 = 0.f, o1 = 0.f, o2 = 0.f;
      #pragma unroll
      for (int i = 0; i < 6; ++i) {
        float x = (hk[kk][i] - mu[kk]) * rstd * lg[i] + lb[i];
        float g = 0.5f * x * (1.0f + erff(x * 0.70710678118654752440f));  // exact gelu
        o0 = fmaf(g, w2a[i], o0); o1 = fmaf(g, w2b[i], o1); o2 = fmaf(g, w2c[i], o2);
      }
      o[kk * 3 + 0] = o0; o[kk * 3 + 1] = o1; o[kk * 3 + 2] = o2;
    }
    wave_sum_arr<15>(o);
    float ox = 0.f, oy = 0.f, oz = 0.f;
    #pragma unroll
    for (int kk = 0; kk < 5; ++kk) {
      if (lane == kb + kk) { ox = o[kk * 3 + 0]; oy = o[kk * 3 + 1]; oz = o[kk * 3 + 2]; }
    }
    if (lane >= kb && lane < kb + 5) {
      const float* mrow = meta + (size_t)bn * 36;
      float lvx = mrow[lane * 3 + 0], lvy = mrow[lane * 3 + 1], lvz = mrow[lane * 3 + 2];
      float sclx = mrow[30], scly = mrow[31], sclz = mrow[32];
      s_shp[lane * 3 + 0] = lvx + tanhf(ox) * sclx;
      s_shp[lane * 3 + 1] = lvy + tanhf(oy) * scly;
      s_shp[lane * 3 + 2] = lvz + tanhf(oz) * sclz;
    }
  }
  __syncthreads();

  // ---- three_nn scan: waves {0,1}->2 points, {2,3}->3 points (exact cnt, balanced) ----
  float wd[3][3]; int wi[3][3];
  int pbase, cnt;
  if (wave < 2) {
    pbase = wave * 2; cnt = 2;
    three_nn_scan<2>(sp4, s_shp, pbase, lane, wd, wi);
  } else {
    pbase = 4 + (wave - 2) * 3; cnt = 3;
    three_nn_scan<3>(sp4, s_shp, pbase, lane, wd, wi);
  }
  if (lane == 0) {
    #pragma unroll
    for (int j = 0; j < 3; ++j) {
      if (j < cnt) {
        float w0 = 1.f / (wd[0][j] + 1e-8f), w1 = 1.f / (wd[1][j] + 1e-8f), w2 = 1.f / (wd[2][j] + 1e-8f);
        float s = w0 + w1 + w2;
        int p = pbase + j;
        s_w[p][0] = w0 / s; s_w[p][1] = w1 / s; s_w[p][2] = w2 / s;
        s_i[p][0] = wi[0][j]; s_i[p][1] = wi[1][j]; s_i[p][2] = wi[2][j];
      }
    }
  }
  __syncthreads();

  // ---- final: out[b,n,c] = max_k lrelu( sum_t w*P[i,c] + Bse[bn,c] ) ----
  const float* Pb = Cat_pb + (size_t)b * NN * (2 * CC);
  const float* BseRow = Cat_pb + (size_t)bn * (2 * CC) + CC;
  for (int c = tid; c < CC; c += 256) {
    float base = BseRow[c];
    float best = -1e30f;
    #pragma unroll
    for (int k = 0; k < KK; ++k) {
      float acc = base;
      #pragma unroll
      for (int tt = 0; tt < 3; ++tt)
        acc = fmaf(s_w[k][tt], Pb[(size_t)s_i[k][tt] * (2 * CC) + c], acc);
      acc = acc >= 0.f ? acc : 0.2f * acc;
      best = fmaxf(best, acc);
    }
    out[(size_t)bn * CC + c] = best;
  }
}

extern "C" void kernel_launch(void* const* d_in, const int* in_sizes, int n_in,
                              void* d_out, int out_size, void* d_ws, size_t ws_size,
                              hipStream_t stream) {
  (void)in_sizes; (void)n_in; (void)out_size; (void)ws_size;
  const float* q    = (const float*)d_in[0];
  const float* qpos = (const float*)d_in[1];
  const float* Wv   = (const float*)d_in[2];
  const float* bv   = (const float*)d_in[3];
  const float* W1   = (const float*)d_in[4];
  const float* b1   = (const float*)d_in[5];
  const float* lng  = (const float*)d_in[6];
  const float* lnb  = (const float*)d_in[7];
  const float* W2   = (const float*)d_in[8];
  const float* Wk   = (const float*)d_in[9];
  const float* bk   = (const float*)d_in[10];
  float* out = (float*)d_out;

  float* ws = (float*)d_ws;
  float* Cat_uv = ws; ws += (size_t)BB * NN * 2 * CC;   // [4096][768] U|V
  float* Cat_pb = ws; ws += (size_t)BB * NN * 2 * CC;   // [4096][768] P|Bse
  float* M1p = Cat_pb;                                   // alias: consumed before Cat_pb written
  float* bias_uv = ws; ws += 2 * CC;
  float* bias_pb = ws; ws += 2 * CC;
  float* meta = ws; ws += (size_t)BB * NN * 36;
  unsigned short* qh = (unsigned short*)ws;  ws += (size_t)BB * NN * CC / 2;
  unsigned short* ql = (unsigned short*)ws;  ws += (size_t)BB * NN * CC / 2;
  unsigned short* Wt = (unsigned short*)ws;  ws += (size_t)2 * CC * CC / 2;
  unsigned short* Buvh = (unsigned short*)ws; ws += (size_t)2 * CC * CC / 2;
  unsigned short* Buvl = (unsigned short*)ws; ws += (size_t)2 * CC * CC / 2;
  int* idxk = (int*)ws;

  prep_gemm_kernel<<<dim3(NB_PREP + 72), dim3(256), 0, stream>>>(
      q, W1, b1, bv, bk, Wk, Wv, qh, ql, Wt, bias_uv, bias_pb, M1p);
  pack_uv_split_kernel<<<dim3(CC * 2 * CC / 256), dim3(256), 0, stream>>>(M1p, W1, Buvh, Buvl);
  gemm_knn_kernel<<<dim3(GEMM_NB + BB * NN / 4), dim3(256), 0, stream>>>(
      qh, ql, Buvh, Buvl, Wt, Cat_uv, Cat_pb, bias_uv, bias_pb, qpos, idxk, meta);
  interp_kernel<<<dim3(BB * NN), dim3(256), 0, stream>>>(
      Cat_uv, Cat_pb, lng, lnb, W2, qpos, idxk, meta, out);
}

// Round 14
// 152.873 us; speedup vs baseline: 1.0277x; 1.0277x over previous
//
#include <hip/hip_runtime.h>
#include <math.h>

#define BB 4
#define NN 1024
#define CC 384
#define KK 10
#define NKK (NN*KK)

typedef __attribute__((ext_vector_type(8))) short short8v;
typedef __attribute__((ext_vector_type(8))) unsigned short ushort8v;
typedef __attribute__((ext_vector_type(4))) float f32x4;

template <int NA>
__device__ __forceinline__ void wave_sum_arr(float* a) {
  #pragma unroll
  for (int off = 32; off > 0; off >>= 1) {
    float t[NA];
    #pragma unroll
    for (int u = 0; u < NA; ++u) t[u] = __shfl_xor(a[u], off, 64);
    #pragma unroll
    for (int u = 0; u < NA; ++u) a[u] += t[u];
  }
}

__device__ __forceinline__ unsigned short f2bf(float x) {
  unsigned int b = __float_as_uint(x);
  return (unsigned short)((b + 0x7fffu + ((b >> 16) & 1u)) >> 16);  // RNE
}
__device__ __forceinline__ float bf2f(unsigned short h) {
  return __uint_as_float(((unsigned int)h) << 16);
}

// ======== fused prep + M1 split-K GEMM, partitioned by blockIdx ========
#define NB_CVT  (BB * NN * CC / 1024)        // 1536
#define NB_PB   (2 * CC * CC / 256)          // 1152
#define NB_PREP (NB_CVT + NB_PB + 3)
__global__ __launch_bounds__(256) void prep_gemm_kernel(
    const float* __restrict__ q,
    const float* __restrict__ W1, const float* __restrict__ b1,
    const float* __restrict__ bv, const float* __restrict__ bk,
    const float* __restrict__ Wk, const float* __restrict__ Wv,
    unsigned short* __restrict__ qh, unsigned short* __restrict__ ql,
    unsigned short* __restrict__ Wt,
    float* __restrict__ bias_uv, float* __restrict__ bias_pb,
    float* __restrict__ M1p) {
  int blk = blockIdx.x;
  int tid = threadIdx.x;
  if (blk < NB_CVT) {
    int i = (blk * 256 + tid) * 4;
    float4 v = *reinterpret_cast<const float4*>(q + i);
    float x[4] = {v.x, v.y, v.z, v.w};
    #pragma unroll
    for (int j = 0; j < 4; ++j) {
      unsigned short h = f2bf(x[j]);
      qh[i + j] = h;
      ql[i + j] = f2bf(x[j] - bf2f(h));
    }
    return;
  }
  if (blk < NB_CVT + NB_PB) {
    int idx = (blk - NB_CVT) * 256 + tid;    // 768*384
    int n = idx / CC, k = idx % CC;
    float v;
    if (n < CC) v = Wk[(size_t)k * CC + n];
    else        v = Wk[(size_t)CC * CC + k * CC + (n - CC)] - Wk[(size_t)k * CC + (n - CC)];
    Wt[(size_t)n * CC + k] = f2bf(v);
    return;
  }
  if (blk < NB_PREP) {
    int j = (blk - NB_CVT - NB_PB) * 256 + tid;
    if (j >= 2 * CC) return;
    if (j < CC) { bias_uv[j] = 0.f; bias_pb[j] = 0.f; }
    else {
      int c = j - CC;
      float s = b1[c];
      for (int i = 0; i < CC; ++i) s += bv[i] * W1[i * CC + c];
      bias_uv[j] = s;          // c1
      bias_pb[j] = bk[c];
    }
    return;
  }
  // ---- gemm128: M1p[z] = Wv @ W1_top (K-slice z), 72 blocks (3x3x8) ----
  {
    int r = blk - NB_PREP;
    int bx = r % 3, by = (r / 3) % 3, bz = r / 9;
    __shared__ float As[16][132];
    __shared__ float Bs[16][128];
    int tx = tid & 15, ty = tid >> 4;
    int row0 = by * 128, col0 = bx * 128;
    int k0 = bz * 48;
    float acc[8][8] = {};
    int arow = tid >> 2, akc = (tid & 3) << 2;
    int brow = tid >> 5, bcol = (tid & 31) << 2;
    for (int kt = k0; kt < k0 + 48; kt += 16) {
      #pragma unroll
      for (int h = 0; h < 2; ++h) {
        int rr = arow + 64 * h;
        float4 av = *reinterpret_cast<const float4*>(Wv + (size_t)(row0 + rr) * CC + kt + akc);
        As[akc + 0][rr] = av.x; As[akc + 1][rr] = av.y;
        As[akc + 2][rr] = av.z; As[akc + 3][rr] = av.w;
      }
      #pragma unroll
      for (int h = 0; h < 2; ++h) {
        int rr = brow + 8 * h;
        float4 bv4 = *reinterpret_cast<const float4*>(W1 + (size_t)(kt + rr) * CC + col0 + bcol);
        *reinterpret_cast<float4*>(&Bs[rr][bcol]) = bv4;
      }
      __syncthreads();
      #pragma unroll
      for (int kk = 0; kk < 16; ++kk) {
        float4 a0 = *reinterpret_cast<const float4*>(&As[kk][ty << 2]);
        float4 a1 = *reinterpret_cast<const float4*>(&As[kk][64 + (ty << 2)]);
        float4 b0 = *reinterpret_cast<const float4*>(&Bs[kk][tx << 2]);
        float4 b1 = *reinterpret_cast<const float4*>(&Bs[kk][64 + (tx << 2)]);
        float av_[8] = {a0.x, a0.y, a0.z, a0.w, a1.x, a1.y, a1.z, a1.w};
        float bv_[8] = {b0.x, b0.y, b0.z, b0.w, b1.x, b1.y, b1.z, b1.w};
        #pragma unroll
        for (int i = 0; i < 8; ++i)
          #pragma unroll
          for (int j = 0; j < 8; ++j) acc[i][j] += av_[i] * bv_[j];
      }
      __syncthreads();
    }
    float* Cz = M1p + (size_t)bz * CC * CC;
    #pragma unroll
    for (int i = 0; i < 8; ++i) {
      int row = row0 + (ty << 2) + (i & 3) + ((i & 4) << 4);
      if (row >= CC) continue;
      #pragma unroll
      for (int h = 0; h < 2; ++h) {
        int col = col0 + 64 * h + (tx << 2);
        if (col >= CC) continue;
        float4 rv;
        rv.x = acc[i][4 * h + 0]; rv.y = acc[i][4 * h + 1];
        rv.z = acc[i][4 * h + 2]; rv.w = acc[i][4 * h + 3];
        *reinterpret_cast<float4*>(Cz + (size_t)row * CC + col) = rv;
      }
    }
  }
}

// ------- Buv_t[n][k] = (n<384 ? M1[k][n] : W1_bot[k][n-384]) split hi/lo -------------
__global__ void pack_uv_split_kernel(const float* __restrict__ M1p, const float* __restrict__ W1,
                                     unsigned short* __restrict__ Buvh,
                                     unsigned short* __restrict__ Buvl) {
  int idx = blockIdx.x * 256 + threadIdx.x;   // 384*768
  int k = idx / (2 * CC), n = idx % (2 * CC);
  float val;
  if (n < CC) {
    float s = 0.f;
    #pragma unroll
    for (int p = 0; p < 8; ++p) s += M1p[(size_t)p * CC * CC + (size_t)k * CC + n];
    val = s;
  } else {
    val = W1[(size_t)(CC + k) * CC + (n - CC)];
  }
  unsigned short h = f2bf(val);
  Buvh[(size_t)n * CC + k] = h;
  Buvl[(size_t)n * CC + k] = f2bf(val - bf2f(h));
}

// ======== fused: [0,384) MFMA GEMM (verified) + [384,1408) knn (verified r10) ========
#define GEMM_NB 384   // 2 paths x 32 by x 6 bx
__global__ __launch_bounds__(256) void gemm_knn_kernel(
    const unsigned short* __restrict__ qh, const unsigned short* __restrict__ ql,
    const unsigned short* __restrict__ Buvh, const unsigned short* __restrict__ Buvl,
    const unsigned short* __restrict__ Wt,
    float* __restrict__ Cuv, float* __restrict__ Cpb,
    const float* __restrict__ bias_uv, const float* __restrict__ bias_pb,
    const float* __restrict__ q_pos, int* __restrict__ idxk, float* __restrict__ meta) {
  __shared__ __align__(16) char smem[32768];
  int blk = blockIdx.x;
  int tid = threadIdx.x;
  int lane = tid & 63, wave = tid >> 6;

  if (blk < GEMM_NB) {
    // ================= MFMA GEMM path (verbatim) =================
    int path = blk / 192;
    int rem = blk % 192;
    int by = rem / 6, bx = rem % 6;
    unsigned short* Ah  = (unsigned short*)smem;
    unsigned short* Alo = (unsigned short*)(smem + 8192);
    unsigned short* Bhs = (unsigned short*)(smem + 16384);
    unsigned short* Bls = (unsigned short*)(smem + 24576);
    const unsigned short* Bh = path ? Wt : Buvh;
    float* Cm = path ? Cpb : Cuv;
    const float* bias = path ? bias_pb : bias_uv;
    int m0 = by * 128, n0 = bx * 128;
    f32x4 acc[4][4];
    #pragma unroll
    for (int i = 0; i < 4; ++i)
      #pragma unroll
      for (int j = 0; j < 4; ++j) acc[i][j] = (f32x4){0.f, 0.f, 0.f, 0.f};
    int rl = lane & 15, kg = lane >> 4;
    for (int k0 = 0; k0 < CC; k0 += 32) {
      #pragma unroll
      for (int j = 0; j < 2; ++j) {
        int id = tid + 256 * j;
        int r = id >> 2, s = id & 3;
        int sw = (s ^ (r & 3)) * 8;
        *reinterpret_cast<ushort8v*>(Ah + r * 32 + sw) =
            *reinterpret_cast<const ushort8v*>(qh + (size_t)(m0 + r) * CC + k0 + s * 8);
        *reinterpret_cast<ushort8v*>(Bhs + r * 32 + sw) =
            *reinterpret_cast<const ushort8v*>(Bh + (size_t)(n0 + r) * CC + k0 + s * 8);
        if (!path) {
          *reinterpret_cast<ushort8v*>(Alo + r * 32 + sw) =
              *reinterpret_cast<const ushort8v*>(ql + (size_t)(m0 + r) * CC + k0 + s * 8);
          *reinterpret_cast<ushort8v*>(Bls + r * 32 + sw) =
              *reinterpret_cast<const ushort8v*>(Buvl + (size_t)(n0 + r) * CC + k0 + s * 8);
        }
      }
      __syncthreads();
      short8v afh[4], bfh[4], afl[4], bfl[4];
      #pragma unroll
      for (int f = 0; f < 4; ++f) {
        int ar = (wave & 1) * 64 + f * 16 + rl;
        int aof = ar * 32 + (kg ^ (ar & 3)) * 8;
        int br = (wave >> 1) * 64 + f * 16 + rl;
        int bof = br * 32 + (kg ^ (br & 3)) * 8;
        afh[f] = *reinterpret_cast<const short8v*>(Ah + aof);
        bfh[f] = *reinterpret_cast<const short8v*>(Bhs + bof);
        if (!path) {
          afl[f] = *reinterpret_cast<const short8v*>(Alo + aof);
          bfl[f] = *reinterpret_cast<const short8v*>(Bls + bof);
        }
      }
      #pragma unroll
      for (int i = 0; i < 4; ++i) {
        #pragma unroll
        for (int j = 0; j < 4; ++j) {
          acc[i][j] = __builtin_amdgcn_mfma_f32_16x16x32_bf16(afh[i], bfh[j], acc[i][j], 0, 0, 0);
          if (!path) {
            acc[i][j] = __builtin_amdgcn_mfma_f32_16x16x32_bf16(afh[i], bfl[j], acc[i][j], 0, 0, 0);
            acc[i][j] = __builtin_amdgcn_mfma_f32_16x16x32_bf16(afl[i], bfh[j], acc[i][j], 0, 0, 0);
          }
        }
      }
      __syncthreads();
    }
    #pragma unroll
    for (int i = 0; i < 4; ++i) {
      #pragma unroll
      for (int j = 0; j < 4; ++j) {
        int col = n0 + (wave >> 1) * 64 + j * 16 + rl;
        float bcol_v = bias[col];
        #pragma unroll
        for (int r = 0; r < 4; ++r) {
          int row = m0 + (wave & 1) * 64 + i * 16 + kg * 4 + r;
          Cm[(size_t)row * (2 * CC) + col] = acc[i][j][r] + bcol_v;
        }
      }
    }
    return;
  }

  // ================= knn path (verbatim; sp4 in smem union) =================
  {
    int kblk = blk - GEMM_NB;            // [0, 1024)
    int b = kblk >> 8;
    int ng = kblk & 255;
    int n = ng * 4 + wave;
    int bn = b * NN + n;
    float4* sp4 = (float4*)smem;

    const float* qp = q_pos + (size_t)b * NN * 3;
    for (int i = tid; i < NN; i += 256) {
      float x = qp[i * 3 + 0], y = qp[i * 3 + 1], z = qp[i * 3 + 2];
      sp4[i] = (float4){x, y, z, x * x + y * y + z * z};
    }
    __syncthreads();

    int nb[KK];
    {
      float4 me = sp4[n];
      float px = me.x, py = me.y, pz = me.z, sp = me.w;
      float bd[KK]; int bi[KK];
      #pragma unroll
      for (int s = 0; s < KK; ++s) { bd[s] = 1e30f; bi[s] = -1; }
      #pragma unroll 4
      for (int j = 0; j < 16; ++j) {
        int m = lane + (j << 6);
        float4 c = sp4[m];
        float dot = fmaf(px, c.x, fmaf(py, c.y, pz * c.z));
        float d = fmaf(-2.f, dot, sp + c.w);
        d = fmaxf(d, 0.f);
        if (d < bd[KK - 1]) {
          bd[KK - 1] = d; bi[KK - 1] = m;
          #pragma unroll
          for (int s = KK - 1; s >= 1; --s) {
            if (bd[s] < bd[s - 1]) {
              float td = bd[s]; bd[s] = bd[s - 1]; bd[s - 1] = td;
              int ti = bi[s]; bi[s] = bi[s - 1]; bi[s - 1] = ti;
            }
          }
        }
      }
      #pragma unroll
      for (int s = 0; s < KK; ++s) {
        float d = bd[0]; int i = bi[0];
        #pragma unroll
        for (int off = 32; off > 0; off >>= 1) {
          float od = __shfl_xor(d, off, 64);
          int oi = __shfl_xor(i, off, 64);
          if (od < d || (od == d && oi < i)) { d = od; i = oi; }
        }
        if (bi[0] == i) {
          #pragma unroll
          for (int u = 0; u < KK - 1; ++u) { bd[u] = bd[u + 1]; bi[u] = bi[u + 1]; }
          bd[KK - 1] = 1e30f; bi[KK - 1] = -1;
        }
        nb[s] = i;   // uniform across lanes
      }
    }

    float sclx, scly, sclz;
    {
      float mxx = -1e30f, mnx = 1e30f, mxy = -1e30f, mny = 1e30f, mxz = -1e30f, mnz = 1e30f;
      #pragma unroll
      for (int k2 = 0; k2 < KK; ++k2) {
        float4 c = sp4[nb[k2]];
        mxx = fmaxf(mxx, c.x); mnx = fminf(mnx, c.x);
        mxy = fmaxf(mxy, c.y); mny = fminf(mny, c.y);
        mxz = fmaxf(mxz, c.z); mnz = fminf(mnz, c.z);
      }
      sclx = (mxx - mnx) * 0.5f; scly = (mxy - mny) * 0.5f; sclz = (mxz - mnz) * 0.5f;
    }

    int myn = 0;
    #pragma unroll
    for (int k = 0; k < KK; ++k) if (lane == k) myn = nb[k];
    float* mrow = meta + (size_t)bn * 36;
    if (lane < KK) {
      idxk[(size_t)bn * KK + lane] = myn;
      float4 c = sp4[myn];
      mrow[lane * 3 + 0] = c.x;
      mrow[lane * 3 + 1] = c.y;
      mrow[lane * 3 + 2] = c.z;
    }
    if (lane == 0) { mrow[30] = sclx; mrow[31] = scly; mrow[32] = sclz; }
  }
}

// ======== mlp: 2 waves per query (5 k's each), no LDS, no barriers (r10 verified) ====
__global__ __launch_bounds__(256) void mlp_kernel(
    const float* __restrict__ Cat_uv, const float* __restrict__ lng, const float* __restrict__ lnb,
    const float* __restrict__ W2, const int* __restrict__ idxk, const float* __restrict__ meta,
    float* __restrict__ shp) {
  int tid = threadIdx.x;
  int wave = tid >> 6, lane = tid & 63;
  int bn = blockIdx.x * 2 + (wave >> 1);    // 2 queries per block
  int b = bn >> 10;
  int kb = (wave & 1) * 5;                  // k half: 0..4 or 5..9

  int nb5[5];
  #pragma unroll
  for (int kk = 0; kk < 5; ++kk) nb5[kk] = idxk[(size_t)bn * KK + kb + kk];

  float Vv[6], lg[6], lb[6], w2a[6], w2b[6], w2c[6];
  const float* Vrow = Cat_uv + (size_t)bn * (2 * CC) + CC;
  #pragma unroll
  for (int i = 0; i < 6; ++i) {
    int c = lane + (i << 6);
    Vv[i] = Vrow[c];
    lg[i] = lng[c]; lb[i] = lnb[c];
    w2a[i] = W2[c * 3 + 0]; w2b[i] = W2[c * 3 + 1]; w2c[i] = W2[c * 3 + 2];
  }

  float hk[5][6];
  float sum[5];
  #pragma unroll
  for (int kk = 0; kk < 5; ++kk) {
    const float* Urow = Cat_uv + ((size_t)b * NN + nb5[kk]) * (2 * CC);
    float s = 0.f;
    #pragma unroll
    for (int i = 0; i < 6; ++i) {
      hk[kk][i] = Urow[lane + (i << 6)] + Vv[i];
      s += hk[kk][i];
    }
    sum[kk] = s;
  }
  wave_sum_arr<5>(sum);
  float mu[5], var[5];
  #pragma unroll
  for (int kk = 0; kk < 5; ++kk) {
    mu[kk] = sum[kk] * (1.0f / CC);
    float v = 0.f;
    #pragma unroll
    for (int i = 0; i < 6; ++i) { float d = hk[kk][i] - mu[kk]; v += d * d; }
    var[kk] = v;
  }
  wave_sum_arr<5>(var);
  float o[15];
  #pragma unroll
  for (int kk = 0; kk < 5; ++kk) {
    float rstd = 1.0f / sqrtf(var[kk] * (1.0f / CC) + 1e-5f);
    float o0 = 0.f, o1 = 0.f, o2 = 0.f;
    #pragma unroll
    for (int i = 0; i < 6; ++i) {
      float x = (hk[kk][i] - mu[kk]) * rstd * lg[i] + lb[i];
      float g = 0.5f * x * (1.0f + erff(x * 0.70710678118654752440f));  // exact gelu
      o0 = fmaf(g, w2a[i], o0); o1 = fmaf(g, w2b[i], o1); o2 = fmaf(g, w2c[i], o2);
    }
    o[kk * 3 + 0] = o0; o[kk * 3 + 1] = o1; o[kk * 3 + 2] = o2;
  }
  wave_sum_arr<15>(o);
  float ox = 0.f, oy = 0.f, oz = 0.f;
  #pragma unroll
  for (int kk = 0; kk < 5; ++kk) {
    if (lane == kb + kk) { ox = o[kk * 3 + 0]; oy = o[kk * 3 + 1]; oz = o[kk * 3 + 2]; }
  }
  if (lane >= kb && lane < kb + 5) {
    const float* mrow = meta + (size_t)bn * 36;
    float lvx = mrow[lane * 3 + 0], lvy = mrow[lane * 3 + 1], lvz = mrow[lane * 3 + 2];
    float sclx = mrow[30], scly = mrow[31], sclz = mrow[32];
    float* sp = shp + ((size_t)bn * KK + lane) * 3;
    sp[0] = lvx + tanhf(ox) * sclx;
    sp[1] = lvy + tanhf(oy) * scly;
    sp[2] = lvz + tanhf(oz) * sclz;
  }
}

// ---- templated three_nn scan for C points (r13-verified, static arrays) ----
template <int C>
__device__ __forceinline__ void three_nn_scan(
    const float4* sp4, const float* s_shp, int pbase, int lane,
    float (&owd)[3][C], int (&owi)[3][C]) {
  float px[C], py[C], pz[C], ps[C];
  #pragma unroll
  for (int j = 0; j < C; ++j) {
    int p = pbase + j;
    px[j] = s_shp[p * 3 + 0]; py[j] = s_shp[p * 3 + 1]; pz[j] = s_shp[p * 3 + 2];
    ps[j] = fmaf(px[j], px[j], fmaf(py[j], py[j], pz[j] * pz[j]));
  }
  float d0[C], d1[C], d2[C]; int i0[C], i1[C], i2[C];
  #pragma unroll
  for (int j = 0; j < C; ++j) { d0[j] = d1[j] = d2[j] = 1e30f; i0[j] = i1[j] = i2[j] = -1; }
  #pragma unroll 4
  for (int it = 0; it < 16; ++it) {
    int m = lane + (it << 6);
    float4 c = sp4[m];
    #pragma unroll
    for (int j = 0; j < C; ++j) {
      float dot = fmaf(px[j], c.x, fmaf(py[j], c.y, pz[j] * c.z));
      float d = fmaf(-2.f, dot, ps[j] + c.w);
      d = fmaxf(d, 0.f);
      bool c2 = d < d2[j], c1 = d < d1[j], c0 = d < d0[j];
      d2[j] = c1 ? d1[j] : (c2 ? d : d2[j]);  i2[j] = c1 ? i1[j] : (c2 ? m : i2[j]);
      d1[j] = c0 ? d0[j] : (c1 ? d : d1[j]);  i1[j] = c0 ? i0[j] : (c1 ? m : i1[j]);
      d0[j] = c0 ? d : d0[j];                 i0[j] = c0 ? m : i0[j];
    }
  }
  #pragma unroll
  for (int s = 0; s < 3; ++s) {
    float d[C]; int ii[C];
    #pragma unroll
    for (int j = 0; j < C; ++j) { d[j] = d0[j]; ii[j] = i0[j]; }
    #pragma unroll
    for (int off = 32; off > 0; off >>= 1) {
      #pragma unroll
      for (int j = 0; j < C; ++j) {
        float od = __shfl_xor(d[j], off, 64);
        int oi = __shfl_xor(ii[j], off, 64);
        if (od < d[j] || (od == d[j] && oi < ii[j])) { d[j] = od; ii[j] = oi; }
      }
    }
    #pragma unroll
    for (int j = 0; j < C; ++j) {
      if (i0[j] == ii[j]) {
        d0[j] = d1[j]; i0[j] = i1[j]; d1[j] = d2[j]; i1[j] = i2[j]; d2[j] = 1e30f; i2[j] = -1;
      }
      owd[s][j] = d[j]; owi[s][j] = ii[j];
    }
  }
}

// ======== interp v4: 320 threads = 5 waves x exactly 2 points each ========
__global__ __launch_bounds__(320) void interp_kernel(
    const float* __restrict__ Cat_pb, const float* __restrict__ q_pos,
    const float* __restrict__ shp, float* __restrict__ out) {
  int bn = blockIdx.x;
  int b = bn >> 10;
  int tid = threadIdx.x;
  int wave = tid >> 6, lane = tid & 63;
  __shared__ float4 sp4[NN];
  __shared__ float s_shp[KK * 3];
  __shared__ float s_w[KK][3];
  __shared__ int s_i[KK][3];

  const float* qp = q_pos + (size_t)b * NN * 3;
  for (int i = tid; i < NN; i += 320) {
    float x = qp[i * 3 + 0], y = qp[i * 3 + 1], z = qp[i * 3 + 2];
    sp4[i] = (float4){x, y, z, x * x + y * y + z * z};
  }
  if (tid < KK * 3) s_shp[tid] = shp[(size_t)bn * KK * 3 + tid];
  __syncthreads();

  // ---- each wave scans exactly 2 points over all 1024 candidates ----
  int pbase = wave * 2;
  float wd[3][2]; int wi[3][2];
  three_nn_scan<2>(sp4, s_shp, pbase, lane, wd, wi);
  if (lane == 0) {
    #pragma unroll
    for (int j = 0; j < 2; ++j) {
      float w0 = 1.f / (wd[0][j] + 1e-8f), w1 = 1.f / (wd[1][j] + 1e-8f), w2 = 1.f / (wd[2][j] + 1e-8f);
      float s = w0 + w1 + w2;
      int p = pbase + j;
      s_w[p][0] = w0 / s; s_w[p][1] = w1 / s; s_w[p][2] = w2 / s;
      s_i[p][0] = wi[0][j]; s_i[p][1] = wi[1][j]; s_i[p][2] = wi[2][j];
    }
  }
  __syncthreads();

  // ---- final: out[b,n,c] = max_k lrelu( sum_t w*P[i,c] + Bse[bn,c] ) ----
  const float* Pb = Cat_pb + (size_t)b * NN * (2 * CC);
  const float* BseRow = Cat_pb + (size_t)bn * (2 * CC) + CC;
  for (int c = tid; c < CC; c += 320) {
    float base = BseRow[c];
    float best = -1e30f;
    #pragma unroll
    for (int k = 0; k < KK; ++k) {
      float acc = base;
      #pragma unroll
      for (int tt = 0; tt < 3; ++tt)
        acc = fmaf(s_w[k][tt], Pb[(size_t)s_i[k][tt] * (2 * CC) + c], acc);
      acc = acc >= 0.f ? acc : 0.2f * acc;
      best = fmaxf(best, acc);
    }
    out[(size_t)bn * CC + c] = best;
  }
}

extern "C" void kernel_launch(void* const* d_in, const int* in_sizes, int n_in,
                              void* d_out, int out_size, void* d_ws, size_t ws_size,
                              hipStream_t stream) {
  (void)in_sizes; (void)n_in; (void)out_size; (void)ws_size;
  const float* q    = (const float*)d_in[0];
  const float* qpos = (const float*)d_in[1];
  const float* Wv   = (const float*)d_in[2];
  const float* bv   = (const float*)d_in[3];
  const float* W1   = (const float*)d_in[4];
  const float* b1   = (const float*)d_in[5];
  const float* lng  = (const float*)d_in[6];
  const float* lnb  = (const float*)d_in[7];
  const float* W2   = (const float*)d_in[8];
  const float* Wk   = (const float*)d_in[9];
  const float* bk   = (const float*)d_in[10];
  float* out = (float*)d_out;

  float* ws = (float*)d_ws;
  float* Cat_uv = ws; ws += (size_t)BB * NN * 2 * CC;   // [4096][768] U|V
  float* Cat_pb = ws; ws += (size_t)BB * NN * 2 * CC;   // [4096][768] P|Bse
  float* M1p = Cat_pb;                                   // alias: consumed before Cat_pb written
  float* bias_uv = ws; ws += 2 * CC;
  float* bias_pb = ws; ws += 2 * CC;
  float* shp = ws; ws += (size_t)BB * NKK * 3;
  float* meta = ws; ws += (size_t)BB * NN * 36;
  unsigned short* qh = (unsigned short*)ws;  ws += (size_t)BB * NN * CC / 2;
  unsigned short* ql = (unsigned short*)ws;  ws += (size_t)BB * NN * CC / 2;
  unsigned short* Wt = (unsigned short*)ws;  ws += (size_t)2 * CC * CC / 2;
  unsigned short* Buvh = (unsigned short*)ws; ws += (size_t)2 * CC * CC / 2;
  unsigned short* Buvl = (unsigned short*)ws; ws += (size_t)2 * CC * CC / 2;
  int* idxk = (int*)ws;

  prep_gemm_kernel<<<dim3(NB_PREP + 72), dim3(256), 0, stream>>>(
      q, W1, b1, bv, bk, Wk, Wv, qh, ql, Wt, bias_uv, bias_pb, M1p);
  pack_uv_split_kernel<<<dim3(CC * 2 * CC / 256), dim3(256), 0, stream>>>(M1p, W1, Buvh, Buvl);
  gemm_knn_kernel<<<dim3(GEMM_NB + BB * NN / 4), dim3(256), 0, stream>>>(
      qh, ql, Buvh, Buvl, Wt, Cat_uv, Cat_pb, bias_uv, bias_pb, qpos, idxk, meta);
  mlp_kernel<<<dim3(BB * NN / 2), dim3(256), 0, stream>>>(
      Cat_uv, lng, lnb, W2, idxk, meta, shp);
  interp_kernel<<<dim3(BB * NN), dim3(320), 0, stream>>>(
      Cat_pb, qpos, shp, out);
}

// Round 15
// 140.656 us; speedup vs baseline: 1.1170x; 1.0869x over previous
//
#include <hip/hip_runtime.h>
#include <math.h>

#define BB 4
#define NN 1024
#define CC 384
#define KK 10
#define NKK (NN*KK)

typedef __attribute__((ext_vector_type(8))) short short8v;
typedef __attribute__((ext_vector_type(8))) unsigned short ushort8v;
typedef __attribute__((ext_vector_type(4))) float f32x4;

template <int NA>
__device__ __forceinline__ void wave_sum_arr(float* a) {
  #pragma unroll
  for (int off = 32; off > 0; off >>= 1) {
    float t[NA];
    #pragma unroll
    for (int u = 0; u < NA; ++u) t[u] = __shfl_xor(a[u], off, 64);
    #pragma unroll
    for (int u = 0; u < NA; ++u) a[u] += t[u];
  }
}

__device__ __forceinline__ unsigned short f2bf(float x) {
  unsigned int b = __float_as_uint(x);
  return (unsigned short)((b + 0x7fffu + ((b >> 16) & 1u)) >> 16);  // RNE
}
__device__ __forceinline__ float bf2f(unsigned short h) {
  return __uint_as_float(((unsigned int)h) << 16);
}

// ======== fused prep + M1 split-K GEMM, partitioned by blockIdx ========
#define NB_CVT  (BB * NN * CC / 1024)        // 1536
#define NB_PB   (2 * CC * CC / 256)          // 1152
#define NB_PREP (NB_CVT + NB_PB + 3)
__global__ __launch_bounds__(256) void prep_gemm_kernel(
    const float* __restrict__ q,
    const float* __restrict__ W1, const float* __restrict__ b1,
    const float* __restrict__ bv, const float* __restrict__ bk,
    const float* __restrict__ Wk, const float* __restrict__ Wv,
    unsigned short* __restrict__ qh, unsigned short* __restrict__ ql,
    unsigned short* __restrict__ Wt,
    float* __restrict__ bias_uv, float* __restrict__ bias_pb,
    float* __restrict__ M1p) {
  int blk = blockIdx.x;
  int tid = threadIdx.x;
  if (blk < NB_CVT) {
    int i = (blk * 256 + tid) * 4;
    float4 v = *reinterpret_cast<const float4*>(q + i);
    float x[4] = {v.x, v.y, v.z, v.w};
    #pragma unroll
    for (int j = 0; j < 4; ++j) {
      unsigned short h = f2bf(x[j]);
      qh[i + j] = h;
      ql[i + j] = f2bf(x[j] - bf2f(h));
    }
    return;
  }
  if (blk < NB_CVT + NB_PB) {
    int idx = (blk - NB_CVT) * 256 + tid;    // 768*384
    int n = idx / CC, k = idx % CC;
    float v;
    if (n < CC) v = Wk[(size_t)k * CC + n];
    else        v = Wk[(size_t)CC * CC + k * CC + (n - CC)] - Wk[(size_t)k * CC + (n - CC)];
    Wt[(size_t)n * CC + k] = f2bf(v);
    return;
  }
  if (blk < NB_PREP) {
    int j = (blk - NB_CVT - NB_PB) * 256 + tid;
    if (j >= 2 * CC) return;
    if (j < CC) { bias_uv[j] = 0.f; bias_pb[j] = 0.f; }
    else {
      int c = j - CC;
      float s = b1[c];
      for (int i = 0; i < CC; ++i) s += bv[i] * W1[i * CC + c];
      bias_uv[j] = s;          // c1
      bias_pb[j] = bk[c];
    }
    return;
  }
  // ---- gemm128: M1p[z] = Wv @ W1_top (K-slice z), 72 blocks (3x3x8) ----
  {
    int r = blk - NB_PREP;
    int bx = r % 3, by = (r / 3) % 3, bz = r / 9;
    __shared__ float As[16][132];
    __shared__ float Bs[16][128];
    int tx = tid & 15, ty = tid >> 4;
    int row0 = by * 128, col0 = bx * 128;
    int k0 = bz * 48;
    float acc[8][8] = {};
    int arow = tid >> 2, akc = (tid & 3) << 2;
    int brow = tid >> 5, bcol = (tid & 31) << 2;
    for (int kt = k0; kt < k0 + 48; kt += 16) {
      #pragma unroll
      for (int h = 0; h < 2; ++h) {
        int rr = arow + 64 * h;
        float4 av = *reinterpret_cast<const float4*>(Wv + (size_t)(row0 + rr) * CC + kt + akc);
        As[akc + 0][rr] = av.x; As[akc + 1][rr] = av.y;
        As[akc + 2][rr] = av.z; As[akc + 3][rr] = av.w;
      }
      #pragma unroll
      for (int h = 0; h < 2; ++h) {
        int rr = brow + 8 * h;
        float4 bv4 = *reinterpret_cast<const float4*>(W1 + (size_t)(kt + rr) * CC + col0 + bcol);
        *reinterpret_cast<float4*>(&Bs[rr][bcol]) = bv4;
      }
      __syncthreads();
      #pragma unroll
      for (int kk = 0; kk < 16; ++kk) {
        float4 a0 = *reinterpret_cast<const float4*>(&As[kk][ty << 2]);
        float4 a1 = *reinterpret_cast<const float4*>(&As[kk][64 + (ty << 2)]);
        float4 b0 = *reinterpret_cast<const float4*>(&Bs[kk][tx << 2]);
        float4 b1 = *reinterpret_cast<const float4*>(&Bs[kk][64 + (tx << 2)]);
        float av_[8] = {a0.x, a0.y, a0.z, a0.w, a1.x, a1.y, a1.z, a1.w};
        float bv_[8] = {b0.x, b0.y, b0.z, b0.w, b1.x, b1.y, b1.z, b1.w};
        #pragma unroll
        for (int i = 0; i < 8; ++i)
          #pragma unroll
          for (int j = 0; j < 8; ++j) acc[i][j] += av_[i] * bv_[j];
      }
      __syncthreads();
    }
    float* Cz = M1p + (size_t)bz * CC * CC;
    #pragma unroll
    for (int i = 0; i < 8; ++i) {
      int row = row0 + (ty << 2) + (i & 3) + ((i & 4) << 4);
      if (row >= CC) continue;
      #pragma unroll
      for (int h = 0; h < 2; ++h) {
        int col = col0 + 64 * h + (tx << 2);
        if (col >= CC) continue;
        float4 rv;
        rv.x = acc[i][4 * h + 0]; rv.y = acc[i][4 * h + 1];
        rv.z = acc[i][4 * h + 2]; rv.w = acc[i][4 * h + 3];
        *reinterpret_cast<float4*>(Cz + (size_t)row * CC + col) = rv;
      }
    }
  }
}

// ------- Buv_t[n][k] = (n<384 ? M1[k][n] : W1_bot[k][n-384]) split hi/lo -------------
__global__ void pack_uv_split_kernel(const float* __restrict__ M1p, const float* __restrict__ W1,
                                     unsigned short* __restrict__ Buvh,
                                     unsigned short* __restrict__ Buvl) {
  int idx = blockIdx.x * 256 + threadIdx.x;   // 384*768
  int k = idx / (2 * CC), n = idx % (2 * CC);
  float val;
  if (n < CC) {
    float s = 0.f;
    #pragma unroll
    for (int p = 0; p < 8; ++p) s += M1p[(size_t)p * CC * CC + (size_t)k * CC + n];
    val = s;
  } else {
    val = W1[(size_t)(CC + k) * CC + (n - CC)];
  }
  unsigned short h = f2bf(val);
  Buvh[(size_t)n * CC + k] = h;
  Buvl[(size_t)n * CC + k] = f2bf(val - bf2f(h));
}

// ======== fused: [0,384) MFMA GEMM (verified) + [384,1408) knn (verified r10) ========
#define GEMM_NB 384   // 2 paths x 32 by x 6 bx
__global__ __launch_bounds__(256) void gemm_knn_kernel(
    const unsigned short* __restrict__ qh, const unsigned short* __restrict__ ql,
    const unsigned short* __restrict__ Buvh, const unsigned short* __restrict__ Buvl,
    const unsigned short* __restrict__ Wt,
    float* __restrict__ Cuv, float* __restrict__ Cpb,
    const float* __restrict__ bias_uv, const float* __restrict__ bias_pb,
    const float* __restrict__ q_pos, int* __restrict__ idxk, float* __restrict__ meta) {
  __shared__ __align__(16) char smem[32768];
  int blk = blockIdx.x;
  int tid = threadIdx.x;
  int lane = tid & 63, wave = tid >> 6;

  if (blk < GEMM_NB) {
    // ================= MFMA GEMM path (verbatim) =================
    int path = blk / 192;
    int rem = blk % 192;
    int by = rem / 6, bx = rem % 6;
    unsigned short* Ah  = (unsigned short*)smem;
    unsigned short* Alo = (unsigned short*)(smem + 8192);
    unsigned short* Bhs = (unsigned short*)(smem + 16384);
    unsigned short* Bls = (unsigned short*)(smem + 24576);
    const unsigned short* Bh = path ? Wt : Buvh;
    float* Cm = path ? Cpb : Cuv;
    const float* bias = path ? bias_pb : bias_uv;
    int m0 = by * 128, n0 = bx * 128;
    f32x4 acc[4][4];
    #pragma unroll
    for (int i = 0; i < 4; ++i)
      #pragma unroll
      for (int j = 0; j < 4; ++j) acc[i][j] = (f32x4){0.f, 0.f, 0.f, 0.f};
    int rl = lane & 15, kg = lane >> 4;
    for (int k0 = 0; k0 < CC; k0 += 32) {
      #pragma unroll
      for (int j = 0; j < 2; ++j) {
        int id = tid + 256 * j;
        int r = id >> 2, s = id & 3;
        int sw = (s ^ (r & 3)) * 8;
        *reinterpret_cast<ushort8v*>(Ah + r * 32 + sw) =
            *reinterpret_cast<const ushort8v*>(qh + (size_t)(m0 + r) * CC + k0 + s * 8);
        *reinterpret_cast<ushort8v*>(Bhs + r * 32 + sw) =
            *reinterpret_cast<const ushort8v*>(Bh + (size_t)(n0 + r) * CC + k0 + s * 8);
        if (!path) {
          *reinterpret_cast<ushort8v*>(Alo + r * 32 + sw) =
              *reinterpret_cast<const ushort8v*>(ql + (size_t)(m0 + r) * CC + k0 + s * 8);
          *reinterpret_cast<ushort8v*>(Bls + r * 32 + sw) =
              *reinterpret_cast<const ushort8v*>(Buvl + (size_t)(n0 + r) * CC + k0 + s * 8);
        }
      }
      __syncthreads();
      short8v afh[4], bfh[4], afl[4], bfl[4];
      #pragma unroll
      for (int f = 0; f < 4; ++f) {
        int ar = (wave & 1) * 64 + f * 16 + rl;
        int aof = ar * 32 + (kg ^ (ar & 3)) * 8;
        int br = (wave >> 1) * 64 + f * 16 + rl;
        int bof = br * 32 + (kg ^ (br & 3)) * 8;
        afh[f] = *reinterpret_cast<const short8v*>(Ah + aof);
        bfh[f] = *reinterpret_cast<const short8v*>(Bhs + bof);
        if (!path) {
          afl[f] = *reinterpret_cast<const short8v*>(Alo + aof);
          bfl[f] = *reinterpret_cast<const short8v*>(Bls + bof);
        }
      }
      #pragma unroll
      for (int i = 0; i < 4; ++i) {
        #pragma unroll
        for (int j = 0; j < 4; ++j) {
          acc[i][j] = __builtin_amdgcn_mfma_f32_16x16x32_bf16(afh[i], bfh[j], acc[i][j], 0, 0, 0);
          if (!path) {
            acc[i][j] = __builtin_amdgcn_mfma_f32_16x16x32_bf16(afh[i], bfl[j], acc[i][j], 0, 0, 0);
            acc[i][j] = __builtin_amdgcn_mfma_f32_16x16x32_bf16(afl[i], bfh[j], acc[i][j], 0, 0, 0);
          }
        }
      }
      __syncthreads();
    }
    #pragma unroll
    for (int i = 0; i < 4; ++i) {
      #pragma unroll
      for (int j = 0; j < 4; ++j) {
        int col = n0 + (wave >> 1) * 64 + j * 16 + rl;
        float bcol_v = bias[col];
        #pragma unroll
        for (int r = 0; r < 4; ++r) {
          int row = m0 + (wave & 1) * 64 + i * 16 + kg * 4 + r;
          Cm[(size_t)row * (2 * CC) + col] = acc[i][j][r] + bcol_v;
        }
      }
    }
    return;
  }

  // ================= knn path (verbatim; sp4 in smem union) =================
  {
    int kblk = blk - GEMM_NB;            // [0, 1024)
    int b = kblk >> 8;
    int ng = kblk & 255;
    int n = ng * 4 + wave;
    int bn = b * NN + n;
    float4* sp4 = (float4*)smem;

    const float* qp = q_pos + (size_t)b * NN * 3;
    for (int i = tid; i < NN; i += 256) {
      float x = qp[i * 3 + 0], y = qp[i * 3 + 1], z = qp[i * 3 + 2];
      sp4[i] = (float4){x, y, z, x * x + y * y + z * z};
    }
    __syncthreads();

    int nb[KK];
    {
      float4 me = sp4[n];
      float px = me.x, py = me.y, pz = me.z, sp = me.w;
      float bd[KK]; int bi[KK];
      #pragma unroll
      for (int s = 0; s < KK; ++s) { bd[s] = 1e30f; bi[s] = -1; }
      #pragma unroll 4
      for (int j = 0; j < 16; ++j) {
        int m = lane + (j << 6);
        float4 c = sp4[m];
        float dot = fmaf(px, c.x, fmaf(py, c.y, pz * c.z));
        float d = fmaf(-2.f, dot, sp + c.w);
        d = fmaxf(d, 0.f);
        if (d < bd[KK - 1]) {
          bd[KK - 1] = d; bi[KK - 1] = m;
          #pragma unroll
          for (int s = KK - 1; s >= 1; --s) {
            if (bd[s] < bd[s - 1]) {
              float td = bd[s]; bd[s] = bd[s - 1]; bd[s - 1] = td;
              int ti = bi[s]; bi[s] = bi[s - 1]; bi[s - 1] = ti;
            }
          }
        }
      }
      #pragma unroll
      for (int s = 0; s < KK; ++s) {
        float d = bd[0]; int i = bi[0];
        #pragma unroll
        for (int off = 32; off > 0; off >>= 1) {
          float od = __shfl_xor(d, off, 64);
          int oi = __shfl_xor(i, off, 64);
          if (od < d || (od == d && oi < i)) { d = od; i = oi; }
        }
        if (bi[0] == i) {
          #pragma unroll
          for (int u = 0; u < KK - 1; ++u) { bd[u] = bd[u + 1]; bi[u] = bi[u + 1]; }
          bd[KK - 1] = 1e30f; bi[KK - 1] = -1;
        }
        nb[s] = i;   // uniform across lanes
      }
    }

    float sclx, scly, sclz;
    {
      float mxx = -1e30f, mnx = 1e30f, mxy = -1e30f, mny = 1e30f, mxz = -1e30f, mnz = 1e30f;
      #pragma unroll
      for (int k2 = 0; k2 < KK; ++k2) {
        float4 c = sp4[nb[k2]];
        mxx = fmaxf(mxx, c.x); mnx = fminf(mnx, c.x);
        mxy = fmaxf(mxy, c.y); mny = fminf(mny, c.y);
        mxz = fmaxf(mxz, c.z); mnz = fminf(mnz, c.z);
      }
      sclx = (mxx - mnx) * 0.5f; scly = (mxy - mny) * 0.5f; sclz = (mxz - mnz) * 0.5f;
    }

    int myn = 0;
    #pragma unroll
    for (int k = 0; k < KK; ++k) if (lane == k) myn = nb[k];
    float* mrow = meta + (size_t)bn * 36;
    if (lane < KK) {
      idxk[(size_t)bn * KK + lane] = myn;
      float4 c = sp4[myn];
      mrow[lane * 3 + 0] = c.x;
      mrow[lane * 3 + 1] = c.y;
      mrow[lane * 3 + 2] = c.z;
    }
    if (lane == 0) { mrow[30] = sclx; mrow[31] = scly; mrow[32] = sclz; }
  }
}

// ======== mlp: 2 waves per query (5 k's each), no LDS, no barriers (r10 verified) ====
__global__ __launch_bounds__(256) void mlp_kernel(
    const float* __restrict__ Cat_uv, const float* __restrict__ lng, const float* __restrict__ lnb,
    const float* __restrict__ W2, const int* __restrict__ idxk, const float* __restrict__ meta,
    float* __restrict__ shp) {
  int tid = threadIdx.x;
  int wave = tid >> 6, lane = tid & 63;
  int bn = blockIdx.x * 2 + (wave >> 1);    // 2 queries per block
  int b = bn >> 10;
  int kb = (wave & 1) * 5;                  // k half: 0..4 or 5..9

  int nb5[5];
  #pragma unroll
  for (int kk = 0; kk < 5; ++kk) nb5[kk] = idxk[(size_t)bn * KK + kb + kk];

  float Vv[6], lg[6], lb[6], w2a[6], w2b[6], w2c[6];
  const float* Vrow = Cat_uv + (size_t)bn * (2 * CC) + CC;
  #pragma unroll
  for (int i = 0; i < 6; ++i) {
    int c = lane + (i << 6);
    Vv[i] = Vrow[c];
    lg[i] = lng[c]; lb[i] = lnb[c];
    w2a[i] = W2[c * 3 + 0]; w2b[i] = W2[c * 3 + 1]; w2c[i] = W2[c * 3 + 2];
  }

  float hk[5][6];
  float sum[5];
  #pragma unroll
  for (int kk = 0; kk < 5; ++kk) {
    const float* Urow = Cat_uv + ((size_t)b * NN + nb5[kk]) * (2 * CC);
    float s = 0.f;
    #pragma unroll
    for (int i = 0; i < 6; ++i) {
      hk[kk][i] = Urow[lane + (i << 6)] + Vv[i];
      s += hk[kk][i];
    }
    sum[kk] = s;
  }
  wave_sum_arr<5>(sum);
  float mu[5], var[5];
  #pragma unroll
  for (int kk = 0; kk < 5; ++kk) {
    mu[kk] = sum[kk] * (1.0f / CC);
    float v = 0.f;
    #pragma unroll
    for (int i = 0; i < 6; ++i) { float d = hk[kk][i] - mu[kk]; v += d * d; }
    var[kk] = v;
  }
  wave_sum_arr<5>(var);
  float o[15];
  #pragma unroll
  for (int kk = 0; kk < 5; ++kk) {
    float rstd = 1.0f / sqrtf(var[kk] * (1.0f / CC) + 1e-5f);
    float o0 = 0.f, o1 = 0.f, o2 = 0.f;
    #pragma unroll
    for (int i = 0; i < 6; ++i) {
      float x = (hk[kk][i] - mu[kk]) * rstd * lg[i] + lb[i];
      float g = 0.5f * x * (1.0f + erff(x * 0.70710678118654752440f));  // exact gelu
      o0 = fmaf(g, w2a[i], o0); o1 = fmaf(g, w2b[i], o1); o2 = fmaf(g, w2c[i], o2);
    }
    o[kk * 3 + 0] = o0; o[kk * 3 + 1] = o1; o[kk * 3 + 2] = o2;
  }
  wave_sum_arr<15>(o);
  float ox = 0.f, oy = 0.f, oz = 0.f;
  #pragma unroll
  for (int kk = 0; kk < 5; ++kk) {
    if (lane == kb + kk) { ox = o[kk * 3 + 0]; oy = o[kk * 3 + 1]; oz = o[kk * 3 + 2]; }
  }
  if (lane >= kb && lane < kb + 5) {
    const float* mrow = meta + (size_t)bn * 36;
    float lvx = mrow[lane * 3 + 0], lvy = mrow[lane * 3 + 1], lvz = mrow[lane * 3 + 2];
    float sclx = mrow[30], scly = mrow[31], sclz = mrow[32];
    float* sp = shp + ((size_t)bn * KK + lane) * 3;
    sp[0] = lvx + tanhf(ox) * sclx;
    sp[1] = lvy + tanhf(oy) * scly;
    sp[2] = lvz + tanhf(oz) * sclz;
  }
}

// ======== interp (r10/r12 verified): three_nn shared-scan batched + final ========
__global__ __launch_bounds__(256) void interp_kernel(
    const float* __restrict__ Cat_pb, const float* __restrict__ q_pos,
    const float* __restrict__ shp, float* __restrict__ out) {
  int bn = blockIdx.x;
  int b = bn >> 10;
  int tid = threadIdx.x;
  int wave = tid >> 6, lane = tid & 63;
  __shared__ float4 sp4[NN];
  __shared__ float s_shp[KK * 3];
  __shared__ float s_w[KK][3];
  __shared__ int s_i[KK][3];

  const float* qp = q_pos + (size_t)b * NN * 3;
  for (int i = tid; i < NN; i += 256) {
    float x = qp[i * 3 + 0], y = qp[i * 3 + 1], z = qp[i * 3 + 2];
    sp4[i] = (float4){x, y, z, x * x + y * y + z * z};
  }
  if (tid < KK * 3) s_shp[tid] = shp[(size_t)bn * KK * 3 + tid];
  __syncthreads();

  int cnt = (wave < 2) ? 3 : 2;
  int pbase = (wave < 2) ? wave * 3 : 6 + (wave - 2) * 2;
  float px[3], py[3], pz[3], ps[3];
  #pragma unroll
  for (int j = 0; j < 3; ++j) {
    int p = pbase + (j < cnt ? j : cnt - 1);
    px[j] = s_shp[p * 3 + 0]; py[j] = s_shp[p * 3 + 1]; pz[j] = s_shp[p * 3 + 2];
    ps[j] = fmaf(px[j], px[j], fmaf(py[j], py[j], pz[j] * pz[j]));
  }
  float d0[3], d1[3], d2[3]; int i0[3], i1[3], i2[3];
  #pragma unroll
  for (int j = 0; j < 3; ++j) { d0[j] = d1[j] = d2[j] = 1e30f; i0[j] = i1[j] = i2[j] = -1; }
  #pragma unroll 4
  for (int it = 0; it < 16; ++it) {
    int m = lane + (it << 6);
    float4 c = sp4[m];
    #pragma unroll
    for (int j = 0; j < 3; ++j) {
      float dot = fmaf(px[j], c.x, fmaf(py[j], c.y, pz[j] * c.z));
      float d = fmaf(-2.f, dot, ps[j] + c.w);
      d = fmaxf(d, 0.f);
      bool c2 = d < d2[j], c1 = d < d1[j], c0 = d < d0[j];
      d2[j] = c1 ? d1[j] : (c2 ? d : d2[j]);  i2[j] = c1 ? i1[j] : (c2 ? m : i2[j]);
      d1[j] = c0 ? d0[j] : (c1 ? d : d1[j]);  i1[j] = c0 ? i0[j] : (c1 ? m : i1[j]);
      d0[j] = c0 ? d : d0[j];                 i0[j] = c0 ? m : i0[j];
    }
  }
  float wd[3][3]; int wi[3][3];
  #pragma unroll
  for (int s = 0; s < 3; ++s) {
    float d[3]; int ii[3];
    #pragma unroll
    for (int j = 0; j < 3; ++j) { d[j] = d0[j]; ii[j] = i0[j]; }
    #pragma unroll
    for (int off = 32; off > 0; off >>= 1) {
      #pragma unroll
      for (int j = 0; j < 3; ++j) {
        float od = __shfl_xor(d[j], off, 64);
        int oi = __shfl_xor(ii[j], off, 64);
        if (od < d[j] || (od == d[j] && oi < ii[j])) { d[j] = od; ii[j] = oi; }
      }
    }
    #pragma unroll
    for (int j = 0; j < 3; ++j) {
      if (i0[j] == ii[j]) {
        d0[j] = d1[j]; i0[j] = i1[j]; d1[j] = d2[j]; i1[j] = i2[j]; d2[j] = 1e30f; i2[j] = -1;
      }
      wd[s][j] = d[j]; wi[s][j] = ii[j];
    }
  }
  if (lane == 0) {
    #pragma unroll
    for (int j = 0; j < 3; ++j) {
      if (j < cnt) {
        float w0 = 1.f / (wd[0][j] + 1e-8f), w1 = 1.f / (wd[1][j] + 1e-8f), w2 = 1.f / (wd[2][j] + 1e-8f);
        float s = w0 + w1 + w2;
        int p = pbase + j;
        s_w[p][0] = w0 / s; s_w[p][1] = w1 / s; s_w[p][2] = w2 / s;
        s_i[p][0] = wi[0][j]; s_i[p][1] = wi[1][j]; s_i[p][2] = wi[2][j];
      }
    }
  }
  __syncthreads();

  const float* Pb = Cat_pb + (size_t)b * NN * (2 * CC);
  const float* BseRow = Cat_pb + (size_t)bn * (2 * CC) + CC;
  for (int c = tid; c < CC; c += 256) {
    float base = BseRow[c];
    float best = -1e30f;
    #pragma unroll
    for (int k = 0; k < KK; ++k) {
      float acc = base;
      #pragma unroll
      for (int tt = 0; tt < 3; ++tt)
        acc = fmaf(s_w[k][tt], Pb[(size_t)s_i[k][tt] * (2 * CC) + c], acc);
      acc = acc >= 0.f ? acc : 0.2f * acc;
      best = fmaxf(best, acc);
    }
    out[(size_t)bn * CC + c] = best;
  }
}

extern "C" void kernel_launch(void* const* d_in, const int* in_sizes, int n_in,
                              void* d_out, int out_size, void* d_ws, size_t ws_size,
                              hipStream_t stream) {
  (void)in_sizes; (void)n_in; (void)out_size; (void)ws_size;
  const float* q    = (const float*)d_in[0];
  const float* qpos = (const float*)d_in[1];
  const float* Wv   = (const float*)d_in[2];
  const float* bv   = (const float*)d_in[3];
  const float* W1   = (const float*)d_in[4];
  const float* b1   = (const float*)d_in[5];
  const float* lng  = (const float*)d_in[6];
  const float* lnb  = (const float*)d_in[7];
  const float* W2   = (const float*)d_in[8];
  const float* Wk   = (const float*)d_in[9];
  const float* bk   = (const float*)d_in[10];
  float* out = (float*)d_out;

  float* ws = (float*)d_ws;
  float* Cat_uv = ws; ws += (size_t)BB * NN * 2 * CC;   // [4096][768] U|V
  float* Cat_pb = ws; ws += (size_t)BB * NN * 2 * CC;   // [4096][768] P|Bse
  float* M1p = Cat_pb;                                   // alias: consumed before Cat_pb written
  float* bias_uv = ws; ws += 2 * CC;
  float* bias_pb = ws; ws += 2 * CC;
  float* shp = ws; ws += (size_t)BB * NKK * 3;
  float* meta = ws; ws += (size_t)BB * NN * 36;
  unsigned short* qh = (unsigned short*)ws;  ws += (size_t)BB * NN * CC / 2;
  unsigned short* ql = (unsigned short*)ws;  ws += (size_t)BB * NN * CC / 2;
  unsigned short* Wt = (unsigned short*)ws;  ws += (size_t)2 * CC * CC / 2;
  unsigned short* Buvh = (unsigned short*)ws; ws += (size_t)2 * CC * CC / 2;
  unsigned short* Buvl = (unsigned short*)ws; ws += (size_t)2 * CC * CC / 2;
  int* idxk = (int*)ws;

  prep_gemm_kernel<<<dim3(NB_PREP + 72), dim3(256), 0, stream>>>(
      q, W1, b1, bv, bk, Wk, Wv, qh, ql, Wt, bias_uv, bias_pb, M1p);
  pack_uv_split_kernel<<<dim3(CC * 2 * CC / 256), dim3(256), 0, stream>>>(M1p, W1, Buvh, Buvl);
  gemm_knn_kernel<<<dim3(GEMM_NB + BB * NN / 4), dim3(256), 0, stream>>>(
      qh, ql, Buvh, Buvl, Wt, Cat_uv, Cat_pb, bias_uv, bias_pb, qpos, idxk, meta);
  mlp_kernel<<<dim3(BB * NN / 2), dim3(256), 0, stream>>>(
      Cat_uv, lng, lnb, W2, idxk, meta, shp);
  interp_kernel<<<dim3(BB * NN), dim3(256), 0, stream>>>(
      Cat_pb, qpos, shp, out);
}